// Round 7
// baseline (144.172 us; speedup 1.0000x reference)
//
#include <hip/hip_runtime.h>
#include <hip/hip_bf16.h>

#define B_DIM 64
#define H_DIM 256
#define NCHG 8            // persistent groups (grid y)
#define CHUNKS 4          // chunks per block
#define TCH 64            // t-rows per chunk
#define NEG_INF -1e12f

typedef __attribute__((ext_vector_type(8))) short short8;
typedef __attribute__((ext_vector_type(4))) float f32x4;

__device__ __forceinline__ unsigned short bfbits(float f) {
    __hip_bfloat16 h = __float2bfloat16(f);
    unsigned short u;
    __builtin_memcpy(&u, &h, 2);
    return u;
}
__device__ __forceinline__ float fast_tanh(float x) {
    float e = __expf(2.0f * x);
    return 1.0f - 2.0f / (e + 1.0f);
}
__device__ __forceinline__ float fast_sigmoid(float x) {
    return 1.0f / (1.0f + __expf(-x));
}

// K0: fused WmT prep (blocks 0..255) + qs GEMV (blocks 256..319)
__global__ void prep_qs_kernel(const float* __restrict__ W_a1,
                               const float* __restrict__ input,
                               const float* __restrict__ state,
                               unsigned short* __restrict__ WmT,
                               float* __restrict__ qs) {
    __shared__ float cat[512];
    int bid = blockIdx.x, tid = threadIdx.x;
    if (bid < 256) {
        WmT[tid * 256 + bid] = bfbits(W_a1[(512 + bid) * 256 + tid]);
    } else {
        int b = bid - 256;
        cat[tid] = input[b * 256 + tid];
        cat[256 + tid] = state[b * 256 + tid];
        __syncthreads();
        int a = tid;
        float s0 = 0.f, s1 = 0.f, s2 = 0.f, s3 = 0.f;
        #pragma unroll 4
        for (int k = 0; k < 512; k += 4) {
            s0 += cat[k]     * W_a1[(k)     * 256 + a];
            s1 += cat[k + 1] * W_a1[(k + 1) * 256 + a];
            s2 += cat[k + 2] * W_a1[(k + 2) * 256 + a];
            s3 += cat[k + 3] * W_a1[(k + 3) * 256 + a];
        }
        qs[b * 256 + a] = (s0 + s1) + (s2 + s3);
    }
}

// K1: persistent attention, reg-resident Wm A-fragments, reg-staged slab,
// 2 barriers per chunk. grid (64, 8) = 512 blocks = 2/CU, 16 waves/CU.
__global__ __launch_bounds__(512, 4) void attn_kernel(
    const float* __restrict__ memory, const int* __restrict__ mask,
    const unsigned short* __restrict__ WmT,
    const float* __restrict__ qs, const float* __restrict__ w_a2,
    float* __restrict__ part_m, float* __restrict__ part_l,
    float* __restrict__ part_acc)
{
    extern __shared__ char smem[];
    unsigned short* slab0 = (unsigned short*)smem;            // [64][256] bf16, swizzled
    unsigned short* slab1 = (unsigned short*)(smem + 32768);
    float* lpart = (float*)(smem + 65536);                    // [8][64]
    int*   maskL = (int*)(smem + 65536 + 2048);               // [256]

    int b = blockIdx.x, g = blockIdx.y;
    int tid = threadIdx.x;
    int lane = tid & 63, w = tid >> 6;
    int lr = lane & 15, lh = lane >> 4;
    int tbase = g * (CHUNKS * TCH);
    const float* mbase = memory + (size_t)tbase * (B_DIM * H_DIM) + b * H_DIM;

    // ---- one-time preloads ----
    // chunk-0 staging (thread covers rows i*8+w, float4 column = lane)
    float4 ld[8];
    #pragma unroll
    for (int i = 0; i < 8; ++i)
        ld[i] = *((const float4*)(mbase + (size_t)(i * 8 + w) * (B_DIM * H_DIM)) + lane);

    // Wm A-fragments -> 64 persistent VGPRs (wave owns a in [w*32, w*32+32))
    int wa0 = w * 32;
    short8 areg[8][2];
    #pragma unroll
    for (int kk = 0; kk < 8; ++kk)
        #pragma unroll
        for (int mf = 0; mf < 2; ++mf)
            areg[kk][mf] = *(const short8*)(WmT + (wa0 + mf * 16 + lr) * 256 + kk * 32 + lh * 8);

    // epilogue constants (lane owns 8 a-values = C rows)
    float qv[2][4], wv[2][4];
    #pragma unroll
    for (int mf = 0; mf < 2; ++mf)
        #pragma unroll
        for (int r = 0; r < 4; ++r) {
            int a = wa0 + mf * 16 + lh * 4 + r;
            qv[mf][r] = qs[b * 256 + a];
            wv[mf][r] = w_a2[a];
        }

    // mask slice for this block (one strided load, once)
    if (tid < CHUNKS * TCH) maskL[tid] = mask[(tbase + tid) * B_DIM + b];

    // write chunk 0 into slab0 (swizzle: byte ^= ((row&7)<<4), row&7 == w)
    int wby = (lane * 8) ^ (w << 4);
    #pragma unroll
    for (int i = 0; i < 8; ++i) {
        ushort4 o;
        o.x = bfbits(ld[i].x); o.y = bfbits(ld[i].y);
        o.z = bfbits(ld[i].z); o.w = bfbits(ld[i].w);
        *(ushort4*)((char*)slab0 + (i * 8 + w) * 512 + wby) = o;
    }
    __syncthreads();

    float a8[8] = {0.f, 0.f, 0.f, 0.f, 0.f, 0.f, 0.f, 0.f};
    float M = -3.4e38f, L = 0.f;
    int slice4 = ((lane >> 5) + 2 * w) * 4;      // PV t-base for this thread
    int hpvb = (lane & 31) * 16;                 // PV h byte-base (8 bf16)

    for (int s = 0; s < CHUNKS; ++s) {
        const char* cur = (const char*)((s & 1) ? slab1 : slab0);
        char* nxt = (char*)((s & 1) ? slab0 : slab1);

        // issue next-chunk global loads (consumed right after MFMA)
        if (s < CHUNKS - 1) {
            #pragma unroll
            for (int i = 0; i < 8; ++i) {
                int row = (s + 1) * TCH + i * 8 + w;
                ld[i] = *((const float4*)(mbase + (size_t)row * (B_DIM * H_DIM)) + lane);
            }
        }

        // ---- MFMA: C[a][t], A from persistent regs, B from LDS only ----
        f32x4 acc[2][4];
        #pragma unroll
        for (int mf = 0; mf < 2; ++mf)
            #pragma unroll
            for (int nf = 0; nf < 4; ++nf)
                acc[mf][nf] = (f32x4){0.f, 0.f, 0.f, 0.f};
        #pragma unroll
        for (int kk = 0; kk < 8; ++kk) {
            int kbyte = kk * 64 + lh * 16;
            #pragma unroll
            for (int nf = 0; nf < 4; ++nf) {
                int t = nf * 16 + lr;
                int sw = kbyte ^ ((t & 7) << 4);
                short8 bfr = *(const short8*)(cur + t * 512 + sw);
                acc[0][nf] = __builtin_amdgcn_mfma_f32_16x16x32_bf16(areg[kk][0], bfr, acc[0][nf], 0, 0, 0);
                acc[1][nf] = __builtin_amdgcn_mfma_f32_16x16x32_bf16(areg[kk][1], bfr, acc[1][nf], 0, 0, 0);
            }
        }

        // ---- write next chunk into idle slab (nxt safe since barrier B of s-1) ----
        if (s < CHUNKS - 1) {
            #pragma unroll
            for (int i = 0; i < 8; ++i) {
                ushort4 o;
                o.x = bfbits(ld[i].x); o.y = bfbits(ld[i].y);
                o.z = bfbits(ld[i].z); o.w = bfbits(ld[i].w);
                *(ushort4*)(nxt + (i * 8 + w) * 512 + wby) = o;
            }
        }

        // ---- epilogue: reduce over a (8 in-lane + 2 shuffles) ----
        #pragma unroll
        for (int nf = 0; nf < 4; ++nf) {
            float sv = 0.f;
            #pragma unroll
            for (int mf = 0; mf < 2; ++mf)
                #pragma unroll
                for (int r = 0; r < 4; ++r)
                    sv += wv[mf][r] * fast_tanh(qv[mf][r] + acc[mf][nf][r]);
            sv += __shfl_xor(sv, 16);
            sv += __shfl_xor(sv, 32);
            if (lh == 0) lpart[w * 64 + nf * 16 + lr] = sv;
        }
        __syncthreads();                         // barrier A: lpart ready

        // ---- combine + mask + softmax (every wave, redundant, identical) ----
        float lg = 0.f;
        #pragma unroll
        for (int ww = 0; ww < 8; ++ww) lg += lpart[ww * 64 + lane];
        lg = maskL[s * 64 + lane] ? lg : NEG_INF;
        float mx = lg;
        #pragma unroll
        for (int d = 1; d < 64; d <<= 1) mx = fmaxf(mx, __shfl_xor(mx, d));
        float ex = __expf(lg - mx);
        float sm = ex;
        #pragma unroll
        for (int d = 1; d < 64; d <<= 1) sm += __shfl_xor(sm, d);

        float newM = fmaxf(M, mx);
        float fo = __expf(M - newM);
        L = L * fo + sm * __expf(mx - newM);
        M = newM;
        #pragma unroll
        for (int j = 0; j < 8; ++j) a8[j] *= fo;
        float pself = __expf(lg - M);            // p for t == lane

        // ---- PV from slab[cur]; p via in-wave shuffle ----
        #pragma unroll
        for (int tt = 0; tt < 4; ++tt) {
            int tl = slice4 + tt;
            float pt = __shfl(pself, tl);        // tl in [8w, 8w+8) -> same wave
            int swb = hpvb ^ ((tl & 7) << 4);
            uint4 u = *(const uint4*)(cur + tl * 512 + swb);
            a8[0] += pt * __uint_as_float(u.x << 16);
            a8[1] += pt * __uint_as_float(u.x & 0xFFFF0000u);
            a8[2] += pt * __uint_as_float(u.y << 16);
            a8[3] += pt * __uint_as_float(u.y & 0xFFFF0000u);
            a8[4] += pt * __uint_as_float(u.z << 16);
            a8[5] += pt * __uint_as_float(u.z & 0xFFFF0000u);
            a8[6] += pt * __uint_as_float(u.w << 16);
            a8[7] += pt * __uint_as_float(u.w & 0xFFFF0000u);
        }
        __syncthreads();                         // barrier B: slab swap safe
    }

    // ---- final combine: alias acc2 over slab0 (dead) ----
    float* acc2 = (float*)smem;                  // [16][256]
    int oct = lane & 31, slice = 2 * w + (lane >> 5), h0 = oct * 8;
    *(float4*)(&acc2[slice * 256 + h0])     = (float4){a8[0], a8[1], a8[2], a8[3]};
    *(float4*)(&acc2[slice * 256 + h0 + 4]) = (float4){a8[4], a8[5], a8[6], a8[7]};
    __syncthreads();
    int pidx = g * B_DIM + b;
    if (tid < 256) {
        float ssum = 0.f;
        #pragma unroll
        for (int sl = 0; sl < 16; ++sl) ssum += acc2[sl * 256 + tid];
        part_acc[(size_t)pidx * 256 + tid] = ssum;
    }
    if (tid == 0) { part_m[pidx] = M; part_l[pidx] = L; }
}

// K2: fused merge (8 group-partials -> attn row) + gate GEMV. block = one b.
__global__ void mergegate_kernel(const float* __restrict__ part_m,
                                 const float* __restrict__ part_l,
                                 const float* __restrict__ part_acc,
                                 const float* __restrict__ input,
                                 const float* __restrict__ W_gate,
                                 float* __restrict__ gated) {
    __shared__ float ni[512];
    int b = blockIdx.x, tid = threadIdx.x;
    if (tid >= 256) {
        int k = tid - 256;
        ni[k] = input[b * 256 + k];
    } else {
        int h = tid;
        float M = -3.4e38f;
        #pragma unroll
        for (int c = 0; c < NCHG; ++c) M = fmaxf(M, part_m[c * 64 + b]);
        float L = 0.f, s = 0.f;
        #pragma unroll
        for (int c = 0; c < NCHG; ++c) {
            float sc = __expf(part_m[c * 64 + b] - M);
            L += part_l[c * 64 + b] * sc;
            s += sc * part_acc[(size_t)(c * 64 + b) * 256 + h];
        }
        ni[256 + h] = s / L;
    }
    __syncthreads();
    int j = tid;
    float s0 = 0.f, s1 = 0.f, s2 = 0.f, s3 = 0.f;
    #pragma unroll 4
    for (int k = 0; k < 512; k += 4) {
        s0 += ni[k]     * W_gate[(k)     * 512 + j];
        s1 += ni[k + 1] * W_gate[(k + 1) * 512 + j];
        s2 += ni[k + 2] * W_gate[(k + 2) * 512 + j];
        s3 += ni[k + 3] * W_gate[(k + 3) * 512 + j];
    }
    float s = (s0 + s1) + (s2 + s3);
    gated[b * 512 + j] = ni[j] * fast_sigmoid(s);
}

// K3: GRU cell. grid 256 = (16 b-tiles x 16 h-tiles), block 768.
__global__ __launch_bounds__(768) void gru_kernel(
    const float* __restrict__ gated, const float* __restrict__ state,
    const float* __restrict__ W_ih, const float* __restrict__ W_hh,
    const float* __restrict__ b_ih, const float* __restrict__ b_hh,
    float* __restrict__ out) {
    __shared__ float ld_g[4][512];
    __shared__ float ld_s[4][256];
    __shared__ float xi[3][16][4];
    __shared__ float xh[3][16][4];
    int ht = blockIdx.x & 15, bt = blockIdx.x >> 4;
    int tid = threadIdx.x;
    #pragma unroll
    for (int i = 0; i < 3; ++i) {
        int idx = i * 768 + tid;
        if (idx < 2048) ld_g[idx >> 9][idx & 511] = gated[(bt * 4 + (idx >> 9)) * 512 + (idx & 511)];
    }
    #pragma unroll
    for (int i = 0; i < 2; ++i) {
        int idx = i * 768 + tid;
        if (idx < 1024) ld_s[idx >> 8][idx & 255] = state[(bt * 4 + (idx >> 8)) * 256 + (idx & 255)];
    }

    int gid = tid >> 4, lk = tid & 15;
    int gate = gid >> 4, hl = gid & 15;
    int j = gate * 256 + ht * 16 + hl;

    float4 wi[8], wh[4];
    #pragma unroll
    for (int it = 0; it < 8; ++it)
        wi[it] = *(const float4*)(W_ih + (size_t)j * 512 + it * 64 + lk * 4);
    #pragma unroll
    for (int it = 0; it < 4; ++it)
        wh[it] = *(const float4*)(W_hh + (size_t)j * 256 + it * 64 + lk * 4);
    float bi = b_ih[j], bh = b_hh[j];
    __syncthreads();

    #pragma unroll
    for (int bb = 0; bb < 4; ++bb) {
        float g0 = 0.f, g1 = 0.f;
        #pragma unroll
        for (int it = 0; it < 8; ++it) {
            float4 gv = *(const float4*)(&ld_g[bb][it * 64 + lk * 4]);
            g0 += wi[it].x * gv.x + wi[it].z * gv.z;
            g1 += wi[it].y * gv.y + wi[it].w * gv.w;
        }
        float h0 = 0.f, h1 = 0.f;
        #pragma unroll
        for (int it = 0; it < 4; ++it) {
            float4 sv = *(const float4*)(&ld_s[bb][it * 64 + lk * 4]);
            h0 += wh[it].x * sv.x + wh[it].z * sv.z;
            h1 += wh[it].y * sv.y + wh[it].w * sv.w;
        }
        float gi_ = g0 + g1, gh_ = h0 + h1;
        #pragma unroll
        for (int m = 1; m < 16; m <<= 1) {
            gi_ += __shfl_xor(gi_, m);
            gh_ += __shfl_xor(gh_, m);
        }
        if (lk == 0) { xi[gate][hl][bb] = gi_ + bi; xh[gate][hl][bb] = gh_ + bh; }
    }
    __syncthreads();
    if (tid < 64) {
        int bb = tid >> 4, hl2 = tid & 15;
        float ir = xi[0][hl2][bb], hr = xh[0][hl2][bb];
        float iz = xi[1][hl2][bb], hz = xh[1][hl2][bb];
        float in_ = xi[2][hl2][bb], hn = xh[2][hl2][bb];
        float r = fast_sigmoid(ir + hr);
        float z = fast_sigmoid(iz + hz);
        float n = fast_tanh(in_ + r * hn);
        out[(bt * 4 + bb) * 256 + ht * 16 + hl2] =
            (1.f - z) * n + z * ld_s[bb][ht * 16 + hl2];
    }
}

extern "C" void kernel_launch(void* const* d_in, const int* in_sizes, int n_in,
                              void* d_out, int out_size, void* d_ws, size_t ws_size,
                              hipStream_t stream) {
    const float* input  = (const float*)d_in[0];
    const float* memory = (const float*)d_in[1];
    const int*   mask   = (const int*)d_in[2];
    const float* state  = (const float*)d_in[3];
    const float* W_a1   = (const float*)d_in[4];
    const float* w_a2   = (const float*)d_in[5];
    const float* W_gate = (const float*)d_in[6];
    const float* W_ih   = (const float*)d_in[7];
    const float* W_hh   = (const float*)d_in[8];
    const float* b_ih   = (const float*)d_in[9];
    const float* b_hh   = (const float*)d_in[10];
    float* out = (float*)d_out;

    char* ws = (char*)d_ws;
    unsigned short* WmT = (unsigned short*)(ws + 0);        // 131072 B
    float* qs       = (float*)(ws + 131072);                // 65536 B
    float* gated    = (float*)(ws + 196608);                // 131072 B
    float* part_m   = (float*)(ws + 327680);                // 2048 B
    float* part_l   = (float*)(ws + 331776);                // 2048 B
    float* part_acc = (float*)(ws + 335872);                // 524288 B

    prep_qs_kernel<<<320, 256, 0, stream>>>(W_a1, input, state, WmT, qs);

    (void)hipFuncSetAttribute((const void*)attn_kernel,
                              hipFuncAttributeMaxDynamicSharedMemorySize, 68608);
    attn_kernel<<<dim3(B_DIM, NCHG), 512, 68608, stream>>>(
        memory, mask, WmT, qs, w_a2, part_m, part_l, part_acc);

    mergegate_kernel<<<64, 512, 0, stream>>>(part_m, part_l, part_acc, input, W_gate, gated);
    gru_kernel<<<256, 768, 0, stream>>>(gated, state, W_ih, W_hh, b_ih, b_hh, out);
}

// Round 8
// 97.929 us; speedup vs baseline: 1.4722x; 1.4722x over previous
//
#include <hip/hip_runtime.h>
#include <hip/hip_bf16.h>

#define B_DIM 64
#define H_DIM 256
#define NG 256            // number of attn blocks (row-groups)
#define SUBS 8            // sub-chunks per block
#define RCH 64            // rows per sub-chunk (= 1 t x 64 b)
#define NEG_INF -1e12f

typedef __attribute__((ext_vector_type(8))) short short8;
typedef __attribute__((ext_vector_type(4))) float f32x4;

__device__ __forceinline__ unsigned short bfbits(float f) {
    __hip_bfloat16 h = __float2bfloat16(f);
    unsigned short u;
    __builtin_memcpy(&u, &h, 2);
    return u;
}
__device__ __forceinline__ float fast_tanh(float x) {
    float e = __expf(2.0f * x);
    return 1.0f - 2.0f / (e + 1.0f);
}
__device__ __forceinline__ float fast_sigmoid(float x) {
    return 1.0f / (1.0f + __expf(-x));
}

// K0: fused WmT prep (blocks 0..255) + qs GEMV (blocks 256..319)
__global__ void prep_qs_kernel(const float* __restrict__ W_a1,
                               const float* __restrict__ input,
                               const float* __restrict__ state,
                               unsigned short* __restrict__ WmT,
                               float* __restrict__ qs) {
    __shared__ float cat[512];
    int bid = blockIdx.x, tid = threadIdx.x;
    if (bid < 256) {
        WmT[tid * 256 + bid] = bfbits(W_a1[(512 + bid) * 256 + tid]);
    } else {
        int b = bid - 256;
        cat[tid] = input[b * 256 + tid];
        cat[256 + tid] = state[b * 256 + tid];
        __syncthreads();
        int a = tid;
        float s0 = 0.f, s1 = 0.f, s2 = 0.f, s3 = 0.f;
        #pragma unroll 4
        for (int k = 0; k < 512; k += 4) {
            s0 += cat[k]     * W_a1[(k)     * 256 + a];
            s1 += cat[k + 1] * W_a1[(k + 1) * 256 + a];
            s2 += cat[k + 2] * W_a1[(k + 2) * 256 + a];
            s3 += cat[k + 3] * W_a1[(k + 3) * 256 + a];
        }
        qs[b * 256 + a] = (s0 + s1) + (s2 + s3);
    }
}

// K1: flat-row attention. Rows = flat (t,b) index -> fully CONTIGUOUS global
// stream (no 64KB stride). Block g owns 512 consecutive rows (8 t x 64 b).
// No max-tracking softmax: |logit| <= ||w_a2||_1 ~ 13, so exp(logit) is
// f32-safe; merge is a plain weighted sum. PV partials live in 32 regs/thread.
__global__ __launch_bounds__(512, 2) void attn_kernel(
    const float* __restrict__ memory, const int* __restrict__ mask,
    const unsigned short* __restrict__ WmT,
    const float* __restrict__ qs, const float* __restrict__ w_a2,
    float* __restrict__ part_l, float* __restrict__ part_acc)
{
    extern __shared__ char smem[];
    unsigned short* slab0 = (unsigned short*)smem;            // [64][256] bf16, swizzled
    unsigned short* slab1 = (unsigned short*)(smem + 32768);
    float* qsT   = (float*)(smem + 65536);                    // [256][65] f32, padded
    float* lpart = (float*)(smem + 65536 + 66560);            // [8][64]
    int*   maskL = (int*)(smem + 65536 + 66560 + 2048);       // [512]
    // total 136,192 B -> 1 block/CU

    int g = blockIdx.x;
    int tid = threadIdx.x;
    int lane = tid & 63, w = tid >> 6;
    int lr = lane & 15, lh = lane >> 4;
    const float* mbase = memory + (size_t)g * (512 * H_DIM);  // 512 contiguous rows

    // ---- one-time staging ----
    #pragma unroll
    for (int i = 0; i < 32; ++i) {                            // qsT[a][b] = qs[b][a]
        int idx = i * 512 + tid;
        qsT[(idx & 255) * 65 + (idx >> 8)] = qs[idx];
    }
    maskL[tid] = mask[g * 512 + tid];                         // contiguous!

    int wa0 = w * 32;
    short8 areg[8][2];                                        // Wm fragments, persistent
    #pragma unroll
    for (int kk = 0; kk < 8; ++kk)
        #pragma unroll
        for (int mf = 0; mf < 2; ++mf)
            areg[kk][mf] = *(const short8*)(WmT + (wa0 + mf * 16 + lr) * 256 + kk * 32 + lh * 8);

    float wv[2][4];
    #pragma unroll
    for (int mf = 0; mf < 2; ++mf)
        #pragma unroll
        for (int r = 0; r < 4; ++r)
            wv[mf][r] = w_a2[wa0 + mf * 16 + lh * 4 + r];

    // stage sub-chunk 0 (contiguous 64KB)
    float4 ld[8];
    #pragma unroll
    for (int i = 0; i < 8; ++i)
        ld[i] = *((const float4*)(mbase + (size_t)(i * 8 + w) * H_DIM) + lane);
    int wby = (lane * 8) ^ (w << 4);
    #pragma unroll
    for (int i = 0; i < 8; ++i) {
        ushort4 o;
        o.x = bfbits(ld[i].x); o.y = bfbits(ld[i].y);
        o.z = bfbits(ld[i].z); o.w = bfbits(ld[i].w);
        *(ushort4*)((char*)slab0 + (i * 8 + w) * 512 + wby) = o;
    }
    __syncthreads();

    float a32[32];
    #pragma unroll
    for (int j = 0; j < 32; ++j) a32[j] = 0.f;
    float l_acc = 0.f;

    for (int s = 0; s < SUBS; ++s) {
        const char* cur = (const char*)((s & 1) ? slab1 : slab0);
        char* nxt = (char*)((s & 1) ? slab0 : slab1);

        // issue next sub-chunk loads (contiguous 64KB span)
        if (s < SUBS - 1) {
            #pragma unroll
            for (int i = 0; i < 8; ++i)
                ld[i] = *((const float4*)(mbase + (size_t)((s + 1) * RCH + i * 8 + w) * H_DIM) + lane);
        }

        // ---- MFMA: C[a][row], A persistent regs, B from LDS ----
        f32x4 acc[2][4];
        #pragma unroll
        for (int mf = 0; mf < 2; ++mf)
            #pragma unroll
            for (int nf = 0; nf < 4; ++nf)
                acc[mf][nf] = (f32x4){0.f, 0.f, 0.f, 0.f};
        #pragma unroll
        for (int kk = 0; kk < 8; ++kk) {
            int kbyte = kk * 64 + lh * 16;
            #pragma unroll
            for (int nf = 0; nf < 4; ++nf) {
                int t = nf * 16 + lr;
                int sw = kbyte ^ ((t & 7) << 4);
                short8 bfr = *(const short8*)(cur + t * 512 + sw);
                acc[0][nf] = __builtin_amdgcn_mfma_f32_16x16x32_bf16(areg[kk][0], bfr, acc[0][nf], 0, 0, 0);
                acc[1][nf] = __builtin_amdgcn_mfma_f32_16x16x32_bf16(areg[kk][1], bfr, acc[1][nf], 0, 0, 0);
            }
        }

        // write next sub-chunk into idle slab (safe since barrier B of s-1)
        if (s < SUBS - 1) {
            #pragma unroll
            for (int i = 0; i < 8; ++i) {
                ushort4 o;
                o.x = bfbits(ld[i].x); o.y = bfbits(ld[i].y);
                o.z = bfbits(ld[i].z); o.w = bfbits(ld[i].w);
                *(ushort4*)(nxt + (i * 8 + w) * 512 + wby) = o;
            }
        }

        // ---- epilogue: logit partial per row; qs from LDS (b = row now) ----
        #pragma unroll
        for (int nf = 0; nf < 4; ++nf) {
            int brow = nf * 16 + lr;
            float sv = 0.f;
            #pragma unroll
            for (int mf = 0; mf < 2; ++mf)
                #pragma unroll
                for (int r = 0; r < 4; ++r) {
                    int a = wa0 + mf * 16 + lh * 4 + r;
                    sv += wv[mf][r] * fast_tanh(qsT[a * 65 + brow] + acc[mf][nf][r]);
                }
            sv += __shfl_xor(sv, 16);
            sv += __shfl_xor(sv, 32);
            if (lh == 0) lpart[w * 64 + brow] = sv;
        }
        __syncthreads();                          // barrier A: lpart ready

        // ---- p = exp(logit) (no max subtraction), PV accumulate ----
        // thread role: b = lane, h-slice = [w*32, w*32+32)
        float lg = 0.f;
        #pragma unroll
        for (int ww = 0; ww < 8; ++ww) lg += lpart[ww * 64 + lane];
        float p = maskL[s * 64 + lane] ? __expf(lg) : 0.f;
        if (w == 0) l_acc += p;

        #pragma unroll
        for (int j = 0; j < 4; ++j) {
            int swb = (w * 64 + j * 16) ^ ((lane & 7) << 4);
            uint4 u = *(const uint4*)(cur + lane * 512 + swb);
            a32[j * 8 + 0] += p * __uint_as_float(u.x << 16);
            a32[j * 8 + 1] += p * __uint_as_float(u.x & 0xFFFF0000u);
            a32[j * 8 + 2] += p * __uint_as_float(u.y << 16);
            a32[j * 8 + 3] += p * __uint_as_float(u.y & 0xFFFF0000u);
            a32[j * 8 + 4] += p * __uint_as_float(u.z << 16);
            a32[j * 8 + 5] += p * __uint_as_float(u.z & 0xFFFF0000u);
            a32[j * 8 + 6] += p * __uint_as_float(u.w << 16);
            a32[j * 8 + 7] += p * __uint_as_float(u.w & 0xFFFF0000u);
        }
        __syncthreads();                          // barrier B: slab swap safe
    }

    // ---- dump PV regs -> LDS (reuse qsT area), write coalesced partials ----
    float* acc2 = qsT;                            // [64][257] f32 (65,792 B)
    #pragma unroll
    for (int j4 = 0; j4 < 8; ++j4)
        *(float4*)(&acc2[lane * 257 + w * 32 + j4 * 4]) =
            (float4){a32[j4 * 4 + 0], a32[j4 * 4 + 1], a32[j4 * 4 + 2], a32[j4 * 4 + 3]};
    __syncthreads();
    int hh = tid & 255, bq = tid >> 8;
    for (int bb = bq; bb < 64; bb += 2)
        part_acc[((size_t)bb * NG + g) * 256 + hh] = acc2[bb * 257 + hh];
    if (w == 0) part_l[lane * NG + g] = l_acc;
}

// K2: fused merge (sum over 256 row-groups) + gate GEMV. block = one b.
__global__ void mergegate_kernel(const float* __restrict__ part_l,
                                 const float* __restrict__ part_acc,
                                 const float* __restrict__ input,
                                 const float* __restrict__ W_gate,
                                 float* __restrict__ gated) {
    __shared__ float ni[512];
    __shared__ float lbuf[256];
    int b = blockIdx.x, tid = threadIdx.x;
    if (tid < 256) lbuf[tid] = part_l[b * NG + tid];
    __syncthreads();
    for (int off = 128; off > 0; off >>= 1) {
        if (tid < off) lbuf[tid] += lbuf[tid + off];
        __syncthreads();
    }
    float L = lbuf[0];
    if (tid < 256) {
        ni[tid] = input[b * 256 + tid];
    } else {
        int h = tid - 256;
        const float* pa = part_acc + (size_t)b * NG * 256 + h;
        float s = 0.f;
        #pragma unroll 8
        for (int g2 = 0; g2 < NG; ++g2) s += pa[(size_t)g2 * 256];
        ni[256 + h] = s / L;
    }
    __syncthreads();
    int j = tid;
    float s0 = 0.f, s1 = 0.f, s2 = 0.f, s3 = 0.f;
    #pragma unroll 4
    for (int k = 0; k < 512; k += 4) {
        s0 += ni[k]     * W_gate[(k)     * 512 + j];
        s1 += ni[k + 1] * W_gate[(k + 1) * 512 + j];
        s2 += ni[k + 2] * W_gate[(k + 2) * 512 + j];
        s3 += ni[k + 3] * W_gate[(k + 3) * 512 + j];
    }
    float s = (s0 + s1) + (s2 + s3);
    gated[b * 512 + j] = ni[j] * fast_sigmoid(s);
}

// K3: GRU cell. grid 256 = (16 b-tiles x 16 h-tiles), block 768.
__global__ __launch_bounds__(768) void gru_kernel(
    const float* __restrict__ gated, const float* __restrict__ state,
    const float* __restrict__ W_ih, const float* __restrict__ W_hh,
    const float* __restrict__ b_ih, const float* __restrict__ b_hh,
    float* __restrict__ out) {
    __shared__ float ld_g[4][512];
    __shared__ float ld_s[4][256];
    __shared__ float xi[3][16][4];
    __shared__ float xh[3][16][4];
    int ht = blockIdx.x & 15, bt = blockIdx.x >> 4;
    int tid = threadIdx.x;
    #pragma unroll
    for (int i = 0; i < 3; ++i) {
        int idx = i * 768 + tid;
        if (idx < 2048) ld_g[idx >> 9][idx & 511] = gated[(bt * 4 + (idx >> 9)) * 512 + (idx & 511)];
    }
    #pragma unroll
    for (int i = 0; i < 2; ++i) {
        int idx = i * 768 + tid;
        if (idx < 1024) ld_s[idx >> 8][idx & 255] = state[(bt * 4 + (idx >> 8)) * 256 + (idx & 255)];
    }

    int gid = tid >> 4, lk = tid & 15;
    int gate = gid >> 4, hl = gid & 15;
    int j = gate * 256 + ht * 16 + hl;

    float4 wi[8], wh[4];
    #pragma unroll
    for (int it = 0; it < 8; ++it)
        wi[it] = *(const float4*)(W_ih + (size_t)j * 512 + it * 64 + lk * 4);
    #pragma unroll
    for (int it = 0; it < 4; ++it)
        wh[it] = *(const float4*)(W_hh + (size_t)j * 256 + it * 64 + lk * 4);
    float bi = b_ih[j], bh = b_hh[j];
    __syncthreads();

    #pragma unroll
    for (int bb = 0; bb < 4; ++bb) {
        float g0 = 0.f, g1 = 0.f;
        #pragma unroll
        for (int it = 0; it < 8; ++it) {
            float4 gv = *(const float4*)(&ld_g[bb][it * 64 + lk * 4]);
            g0 += wi[it].x * gv.x + wi[it].z * gv.z;
            g1 += wi[it].y * gv.y + wi[it].w * gv.w;
        }
        float h0 = 0.f, h1 = 0.f;
        #pragma unroll
        for (int it = 0; it < 4; ++it) {
            float4 sv = *(const float4*)(&ld_s[bb][it * 64 + lk * 4]);
            h0 += wh[it].x * sv.x + wh[it].z * sv.z;
            h1 += wh[it].y * sv.y + wh[it].w * sv.w;
        }
        float gi_ = g0 + g1, gh_ = h0 + h1;
        #pragma unroll
        for (int m = 1; m < 16; m <<= 1) {
            gi_ += __shfl_xor(gi_, m);
            gh_ += __shfl_xor(gh_, m);
        }
        if (lk == 0) { xi[gate][hl][bb] = gi_ + bi; xh[gate][hl][bb] = gh_ + bh; }
    }
    __syncthreads();
    if (tid < 64) {
        int bb = tid >> 4, hl2 = tid & 15;
        float ir = xi[0][hl2][bb], hr = xh[0][hl2][bb];
        float iz = xi[1][hl2][bb], hz = xh[1][hl2][bb];
        float in_ = xi[2][hl2][bb], hn = xh[2][hl2][bb];
        float r = fast_sigmoid(ir + hr);
        float z = fast_sigmoid(iz + hz);
        float n = fast_tanh(in_ + r * hn);
        out[(bt * 4 + bb) * 256 + ht * 16 + hl2] =
            (1.f - z) * n + z * ld_s[bb][ht * 16 + hl2];
    }
}

extern "C" void kernel_launch(void* const* d_in, const int* in_sizes, int n_in,
                              void* d_out, int out_size, void* d_ws, size_t ws_size,
                              hipStream_t stream) {
    const float* input  = (const float*)d_in[0];
    const float* memory = (const float*)d_in[1];
    const int*   mask   = (const int*)d_in[2];
    const float* state  = (const float*)d_in[3];
    const float* W_a1   = (const float*)d_in[4];
    const float* w_a2   = (const float*)d_in[5];
    const float* W_gate = (const float*)d_in[6];
    const float* W_ih   = (const float*)d_in[7];
    const float* W_hh   = (const float*)d_in[8];
    const float* b_ih   = (const float*)d_in[9];
    const float* b_hh   = (const float*)d_in[10];
    float* out = (float*)d_out;

    char* ws = (char*)d_ws;
    unsigned short* WmT = (unsigned short*)(ws + 0);        // 131072 B
    float* qs       = (float*)(ws + 131072);                // 65536 B
    float* gated    = (float*)(ws + 196608);                // 131072 B
    float* part_l   = (float*)(ws + 327680);                // 65536 B (64 x 256)
    float* part_acc = (float*)(ws + 393216);                // 16777216 B (64 x 256 x 256)

    prep_qs_kernel<<<320, 256, 0, stream>>>(W_a1, input, state, WmT, qs);

    (void)hipFuncSetAttribute((const void*)attn_kernel,
                              hipFuncAttributeMaxDynamicSharedMemorySize, 136192);
    attn_kernel<<<NG, 512, 136192, stream>>>(
        memory, mask, WmT, qs, w_a2, part_l, part_acc);

    mergegate_kernel<<<64, 512, 0, stream>>>(part_l, part_acc, input, W_gate, gated);
    gru_kernel<<<256, 768, 0, stream>>>(gated, state, W_ih, W_hh, b_ih, b_hh, out);
}